// Round 8
// baseline (399.143 us; speedup 1.0000x reference)
//
#include <hip/hip_runtime.h>
#include <stdint.h>

#define M_ROWS 4096
#define N_COLS 16384
#define K_HARD 163          // int(0.01 * (16384 - 1))
#define DELTA_W 5.0f
#define THRESH  2.0f
#define KEY_MIN 0xC0000000u // f2key(2.0f)
#define SLOTS   24          // per (row,wg) segment; mean 5.83, sd 2.36 -> +7.7 sigma
#define WG      64          // wave-groups per row (64 float4 = 256 elems each)
#define GRID1   2048        // 8 blocks/CU -> whole grid resident, dense front
#define T1      256
#define ITERS   32          // 16.78M float4s / (2048*256)

__device__ __forceinline__ uint32_t f2key(float x) {
    uint32_t u = __float_as_uint(x);
    return u ^ (uint32_t)(((int32_t)u >> 31) | 0x80000000u);
}
__device__ __forceinline__ float key2f(uint32_t k) {
    uint32_t u = (k & 0x80000000u) ? (k & 0x7fffffffu) : ~k;
    return __uint_as_float(u);
}
__device__ __forceinline__ float softplus_f(float x) {
    return fmaxf(x, 0.0f) + log1pf(__expf(-fabsf(x)));
}

// Wave-local pivot scan over 1024 ascending bins: find bin P with
// count(bins > P) < K <= count(bins >= P). pivot=P, krem=K-count(bins>P).
// Requires sum(bins) >= K >= 1, K <= 255. All 64 lanes participate.
__device__ __forceinline__ void wscan1024(const uint32_t* h, int lane, int K,
                                          int& pivot, int& krem) {
    int c[16]; int S = 0;
#pragma unroll
    for (int q = 0; q < 16; ++q) { c[q] = (int)h[lane * 16 + q]; S += c[q]; }
    int suf = S;
    for (int off = 1; off < 64; off <<= 1) {
        int y = __shfl_down(suf, off);
        if (lane + off < 64) suf += y;
    }
    int run = suf - S;                     // count in bins strictly above mine
    int enc = 0;
#pragma unroll
    for (int b = 15; b >= 0; --b) {
        const int cc = c[b];
        if (run < K && run + cc >= K) enc = ((lane * 16 + b + 1) << 8) | (K - run);
        run += cc;
    }
    for (int off = 1; off < 64; off <<= 1) enc = max(enc, __shfl_xor(enc, off));
    pivot = (enc >> 8) - 1; krem = enc & 255;
}

// Wave-local exact full-row top-K fallback (never taken on N(0,1) data).
// Returns row softplus-sum on lane 0.
__device__ float wave_fallback(const float4* row4, int tgt, uint32_t* hrow, int lane) {
    uint32_t pref = 0; int K = K_HARD;
    for (int pass = 0; pass < 3; ++pass) {
        const int shift = 22 - 10 * pass;
        for (int q = 0; q < 16; ++q) hrow[q * 64 + lane] = 0;
        for (int s2 = 0; s2 < 64; ++s2) {
            const float4 v = row4[s2 * 64 + lane];
            const int j0 = (s2 * 64 + lane) * 4;
            const float e[4] = {v.x, v.y, v.z, v.w};
#pragma unroll
            for (int q = 0; q < 4; ++q) {
                if (j0 + q == tgt) continue;
                const uint32_t k = f2key(e[q]);
                if (pass == 0 || (k >> (shift + 10)) == pref)
                    atomicAdd(&hrow[(k >> shift) & 1023u], 1u);
            }
        }
        int pv, kr; wscan1024(hrow, lane, K, pv, kr);
        pref = (pref << 10) | (uint32_t)pv; K = kr;
    }
    for (int q = 0; q < 16; ++q) hrow[q * 64 + lane] = 0;
    for (int s2 = 0; s2 < 64; ++s2) {
        const float4 v = row4[s2 * 64 + lane];
        const int j0 = (s2 * 64 + lane) * 4;
        const float e[4] = {v.x, v.y, v.z, v.w};
#pragma unroll
        for (int q = 0; q < 4; ++q) {
            if (j0 + q == tgt) continue;
            const uint32_t k = f2key(e[q]);
            if ((k >> 2) == pref) atomicAdd(&hrow[k & 3u], 1u);
        }
    }
    int piv = 0, tie = K;
    { int run = 0;
      for (int b2 = 3; b2 >= 0; --b2) {
          const int cc = (int)hrow[b2];
          if (run < K && run + cc >= K) { piv = b2; tie = K - run; }
          run += cc;
      } }
    const uint32_t T = (pref << 2) | (uint32_t)piv;
    float sum = 0.0f;
    for (int s2 = 0; s2 < 64; ++s2) {
        const float4 v = row4[s2 * 64 + lane];
        const int j0 = (s2 * 64 + lane) * 4;
        const float e[4] = {v.x, v.y, v.z, v.w};
#pragma unroll
        for (int q = 0; q < 4; ++q) {
            if (j0 + q == tgt) continue;
            const uint32_t k = f2key(e[q]);
            if (k > T) sum += softplus_f(e[q]);
        }
    }
    for (int off = 32; off; off >>= 1) sum += __shfl_down(sum, off);
    if (lane == 0) sum += (float)tie * softplus_f(key2f(T));
    return sum;   // valid on lane 0
}

// ---- K1: copy-style dense grid-stride front; atomic-free bucketing ----
__global__ __launch_bounds__(T1) void k1_front(
        const float* __restrict__ inputs,
        uint32_t* __restrict__ bucket,     // [M_ROWS][WG][SLOTS]
        int* __restrict__ cnts) {          // [M_ROWS][WG]
    const size_t flat = (size_t)blockIdx.x * T1 + threadIdx.x;
    const int lane = threadIdx.x & 63;
    const float4* in4 = (const float4*)inputs;
#pragma unroll 4
    for (int it = 0; it < ITERS; ++it) {
        const size_t g = (size_t)it * ((size_t)GRID1 * T1) + flat;
        const float4 v = in4[g];
        const int row = (int)(g >> 12);            // 4096 float4s per row
        const int wg  = (int)((g >> 6) & 63);      // 64 float4s per wave-group
        const float e[4] = {v.x, v.y, v.z, v.w};
        const int nc = (v.x >= THRESH) + (v.y >= THRESH) +
                       (v.z >= THRESH) + (v.w >= THRESH);
        int inc = nc;
        for (int off = 1; off < 64; off <<= 1) {
            int y = __shfl_up(inc, off);
            if (lane >= off) inc += y;
        }
        uint32_t* seg = bucket + ((size_t)row * WG + wg) * SLOTS;
        int d = inc - nc;
#pragma unroll
        for (int q = 0; q < 4; ++q) {
            if (e[q] >= THRESH) {
                if (d < SLOTS) seg[d] = f2key(e[q]);
                ++d;
            }
        }
        if (lane == 63) cnts[row * WG + wg] = inc;   // wave total, plain store
    }
}

// ---- K2: wave-per-row select from buckets ----
__global__ __launch_bounds__(256) void k2_select(
        const float* __restrict__ inputs,
        const int* __restrict__ targets,
        const uint32_t* __restrict__ bucket,
        const int* __restrict__ cnts,
        float* __restrict__ partial) {
    __shared__ uint32_t sh[4][1024];
    const int wid = threadIdx.x >> 6;
    const int lane = threadIdx.x & 63;
    const int row = blockIdx.x * 4 + wid;
    const int tgt = targets[row];
    const float pos = inputs[(size_t)row * N_COLS + tgt];
    const float4* row4 = (const float4*)(inputs + (size_t)row * N_COLS);
    uint32_t* hrow = sh[wid];

    const int myc = cnts[row * WG + lane];
    int mx = myc, sm = myc;
    for (int off = 1; off < 64; off <<= 1) {
        mx = max(mx, __shfl_xor(mx, off));
        sm += __shfl_xor(sm, off);
    }
    bool fb = (mx > SLOTS);

    // load my segment's keys (lane <-> wave-group)
    uint32_t keys[SLOTS];
    const int c = fb ? 0 : myc;
    const uint32_t* seg = bucket + ((size_t)row * WG + lane) * SLOTS;
#pragma unroll
    for (int q = 0; q < SLOTS; ++q) keys[q] = (q < c) ? seg[q] : 0u;

    // remove exactly one instance of the positive's key
    int removed = 0;
    if (!fb && pos >= THRESH) {
        const uint32_t tkey = f2key(pos);
        int q0 = SLOTS;
        for (int q = SLOTS - 1; q >= 0; --q) if (keys[q] == tkey && q < c) q0 = q;
        const unsigned long long m = __ballot(q0 < SLOTS);
        if (m) {
            const int leader = __ffsll(m) - 1;
            if (lane == leader) keys[q0] = 0u;   // sentinel < KEY_MIN
            removed = 1;
        }
        removed = __shfl(removed, 0);   // uniform (ballot result uniform anyway)
    }
    const int ncand = sm - removed;
    if (ncand < K_HARD) fb = true;

    float sum;
    if (!fb) {
        uint32_t pref = 0; int K = K_HARD; int pv = 0, kr = K_HARD;
#pragma unroll
        for (int pass = 0; pass < 3; ++pass) {
            const int shift = 20 - 10 * pass;
            for (int q = 0; q < 16; ++q) hrow[q * 64 + lane] = 0;
#pragma unroll
            for (int q = 0; q < SLOTS; ++q) {
                const uint32_t k = keys[q];
                if (k >= KEY_MIN) {
                    const uint32_t d = k - KEY_MIN;
                    if (pass == 0 || (d >> (shift + 10)) == pref)
                        atomicAdd(&hrow[(d >> shift) & 1023u], 1u);
                }
            }
            wscan1024(hrow, lane, K, pv, kr);
            pref = (pref << 10) | (uint32_t)pv; K = kr;
        }
        const uint32_t T = KEY_MIN + pref;   // pref = p1<<20|p2<<10|p3
        sum = 0.0f;
#pragma unroll
        for (int q = 0; q < SLOTS; ++q) {
            const uint32_t k = keys[q];
            if (k > T) sum += softplus_f(key2f(k));
        }
        for (int off = 32; off; off >>= 1) sum += __shfl_down(sum, off);
        if (lane == 0) sum += (float)kr * softplus_f(key2f(T));
    } else {
        sum = wave_fallback(row4, tgt, hrow, lane);
    }

    if (lane == 0)
        partial[row] = DELTA_W * softplus_f(-pos) + sum / (float)K_HARD;
}

__global__ __launch_bounds__(256) void mmcl_reduce(
        const float* __restrict__ partial, float* __restrict__ out) {
    __shared__ float s_fw[4];
    const int t = threadIdx.x;
    float local = 0.0f;
    for (int i = t; i < M_ROWS; i += 256) local += partial[i];
    for (int off = 32; off; off >>= 1) local += __shfl_down(local, off);
    if ((t & 63) == 0) s_fw[t >> 6] = local;
    __syncthreads();
    if (t == 0)
        out[0] = (s_fw[0] + s_fw[1] + s_fw[2] + s_fw[3]) * (1.0f / (float)M_ROWS);
}

extern "C" void kernel_launch(void* const* d_in, const int* in_sizes, int n_in,
                              void* d_out, int out_size, void* d_ws, size_t ws_size,
                              hipStream_t stream) {
    const float* inputs = (const float*)d_in[0];
    const int* targets = (const int*)d_in[1];
    float* out = (float*)d_out;
    char* ws = (char*)d_ws;
    int* cnts = (int*)ws;                                 // 1 MB (4096*64*4)
    float* partial = (float*)(ws + (1 << 20));            // 16 KB
    uint32_t* bucket = (uint32_t*)(ws + (2 << 20));       // 24 MB (4096*64*24*4)
    k1_front<<<GRID1, T1, 0, stream>>>(inputs, bucket, cnts);
    k2_select<<<M_ROWS / 4, 256, 0, stream>>>(inputs, targets, bucket, cnts, partial);
    mmcl_reduce<<<1, 256, 0, stream>>>(partial, out);
}